// Round 6
// baseline (34.577 us; speedup 1.0000x reference)
//
#include <hip/hip_runtime.h>
#include <hip/hip_bf16.h>
#include <math.h>

#define D 256
#define NPROTO 1024
#define WR 13
#define WC 18
#define WJ (WR * WC)
#define JSUB 59                    // ceil(WJ/4)
#define GMAT_BLOCKS (NPROTO / 4)   // 256
#define XPREP_BLOCKS (16384 / 8)   // 2048

#define WAITVM(N) asm volatile("s_waitcnt vmcnt(" #N ")" ::: "memory")

typedef __attribute__((ext_vector_type(8))) short short8;
typedef __attribute__((ext_vector_type(4))) float f32x4;

__device__ __forceinline__ short f2bf(float f) {
    union { __hip_bfloat16 b; short s; } u;
    u.b = __float2bfloat16(f);
    return u.s;
}

__device__ __forceinline__ void gload_lds16(void* lds, const void* g) {
    __builtin_amdgcn_global_load_lds(
        (const __attribute__((address_space(1))) unsigned*)g,
        (__attribute__((address_space(3))) unsigned*)lds, 16, 0, 0);
}

// ---- hex-grid neighborhood H[i,j] on the fly (fp64, matches np ref) ----
__device__ __forceinline__ void proto_pos(int idx, double& x, double& y) {
    int r = idx >> 5, c = idx & 31;
    x = (double)c + 0.5 * (double)(r & 1);
    y = (double)r * 0.86602540378443864676;  // sqrt(3)/2
}

__device__ __forceinline__ float hval(int i, int j) {
    double xi, yi, xj, yj;
    proto_pos(i, xi, yi);
    proto_pos(j, xj, yj);
    double dx0 = xi - xj, dy0 = yi - yj;
    const double W = 32.0;
    const double Hh = 27.712812921102035;  // 32*sqrt(3)/2
    double best = 1e300;
#pragma unroll
    for (int sx = -1; sx <= 1; ++sx) {
        double dx = dx0 + (double)sx * W;
#pragma unroll
        for (int sy = -1; sy <= 1; ++sy) {
            double dy = dy0 + (double)sy * Hh;
            double d2 = dx * dx + dy * dy;
            best = fmin(best, d2);
        }
    }
    return (float)exp(-0.5 * best);
}

// ---- prep: role-split single kernel.
//  blocks [0, 256):      gmat — GbF = bf16(H@P) in MFMA B-FRAGMENT order:
//                        tile (Igrp = i>>4, kg = k>>5) is 1KB at
//                        (Igrp*8+kg)*512 shorts; lane (i&15)+16*q holds
//                        G[i][kg*32 + q*8 .. +7].  Also hsum, hp2.
//  blocks [256, 2304):   xprep — Xg = bf16(X) pre-swizzled, x2, out=+inf ----
__global__ void __launch_bounds__(256) prep_kernel(
    const float* __restrict__ X, const float* __restrict__ P,
    short* __restrict__ Xg, short* __restrict__ GbF,
    float* __restrict__ x2, float* __restrict__ hsum, float* __restrict__ hp2,
    unsigned* __restrict__ out) {
    int t = threadIdx.x;
    int bx = blockIdx.x;

    if (bx >= GMAT_BLOCKS) {
        // ---------------- xprep ----------------
        int row = (bx - GMAT_BLOCKS) * 8 + (t >> 5);
        int g = t & 31;
        const float4* src = reinterpret_cast<const float4*>(X + (size_t)row * D) + g * 2;
        float4 a = src[0], b = src[1];
        float s = a.x * a.x + a.y * a.y + a.z * a.z + a.w * a.w +
                  b.x * b.x + b.y * b.y + b.z * b.z + b.w * b.w;
        s += __shfl_xor(s, 1);
        s += __shfl_xor(s, 2);
        s += __shfl_xor(s, 4);
        s += __shfl_xor(s, 8);
        s += __shfl_xor(s, 16);
        if (g == 0) x2[row] = s;
        short8 w;
        w[0] = f2bf(a.x); w[1] = f2bf(a.y); w[2] = f2bf(a.z); w[3] = f2bf(a.w);
        w[4] = f2bf(b.x); w[5] = f2bf(b.y); w[6] = f2bf(b.z); w[7] = f2bf(b.w);
        int sw = ((g * 8) & 63) ^ ((row & 7) << 3);  // short-index swizzle in 64-chunk
        *reinterpret_cast<short8*>(Xg + (size_t)row * D + ((g >> 3) << 6) + sw) = w;
        if (t < 8) out[(bx - GMAT_BLOCKS) * 8 + t] = 0x7f800000u;  // +inf
        return;
    }

    // ---------------- gmat ----------------
    __shared__ float ht[4][WJ];
    __shared__ int jrow[WJ];
    __shared__ __align__(16) float gpart[4][4][256];  // wave x proto x d, 16KB
    __shared__ float hqred[4][4];                     // wave x proto
    __shared__ float hsred[4][4];
    int i0 = bx * 4;
    int r0 = i0 >> 5, c0 = i0 & 31;

    for (int u = t; u < WJ; u += 256) {
        int jr = (r0 + (u / WC) - 6 + 32) & 31;
        int jc = (c0 + (u % WC) - 7 + 32) & 31;
        int j = jr * 32 + jc;
        jrow[u] = j;
#pragma unroll
        for (int s = 0; s < 4; ++s) ht[s][u] = hval(i0 + s, j);
    }
    __syncthreads();

    int w = t >> 6, lane = t & 63;
    int j0 = w * JSUB;
    int j1 = (j0 + JSUB < WJ) ? j0 + JSUB : WJ;
    f32x4 g[4] = {{0.f, 0.f, 0.f, 0.f}, {0.f, 0.f, 0.f, 0.f},
                  {0.f, 0.f, 0.f, 0.f}, {0.f, 0.f, 0.f, 0.f}};
    float hqp[4] = {0.f, 0.f, 0.f, 0.f};
    float hsp[4] = {0.f, 0.f, 0.f, 0.f};
    for (int u = j0; u < j1; ++u) {
        f32x4 pv = *reinterpret_cast<const f32x4*>(P + (size_t)jrow[u] * D + lane * 4);
        float q = pv[0] * pv[0] + pv[1] * pv[1] + pv[2] * pv[2] + pv[3] * pv[3];
#pragma unroll
        for (int s = 0; s < 4; ++s) {
            float h = ht[s][u];
            g[s][0] = fmaf(h, pv[0], g[s][0]);
            g[s][1] = fmaf(h, pv[1], g[s][1]);
            g[s][2] = fmaf(h, pv[2], g[s][2]);
            g[s][3] = fmaf(h, pv[3], g[s][3]);
            hqp[s] = fmaf(h, q, hqp[s]);
            hsp[s] += h;  // lane-uniform
        }
    }
#pragma unroll
    for (int s = 0; s < 4; ++s)
        *reinterpret_cast<f32x4*>(&gpart[w][s][lane * 4]) = g[s];
    // reduce hqp across 64 lanes
#pragma unroll
    for (int s = 0; s < 4; ++s) {
#pragma unroll
        for (int off = 1; off < 64; off <<= 1) hqp[s] += __shfl_xor(hqp[s], off);
    }
    if (lane == 0) {
#pragma unroll
        for (int s = 0; s < 4; ++s) { hqred[w][s] = hqp[s]; hsred[w][s] = hsp[s]; }
    }
    __syncthreads();

    // final: sum partials; write B-FRAGMENT-ordered bf16 (lane pairs -> 8 d's)
    {
        int s = t >> 6;  // proto within block
        f32x4 gs = *reinterpret_cast<const f32x4*>(&gpart[0][s][lane * 4]);
#pragma unroll
        for (int ww = 1; ww < 4; ++ww) {
            f32x4 gp = *reinterpret_cast<const f32x4*>(&gpart[ww][s][lane * 4]);
            gs[0] += gp[0]; gs[1] += gp[1]; gs[2] += gp[2]; gs[3] += gp[3];
        }
        // lane holds d = lane*4..+3; even lane grabs odd lane's 4 -> chunk of 8
        float h0 = __shfl_down(gs[0], 1);
        float h1 = __shfl_down(gs[1], 1);
        float h2 = __shfl_down(gs[2], 1);
        float h3 = __shfl_down(gs[3], 1);
        if (!(lane & 1)) {
            int c = lane >> 1;          // d-chunk: d = c*8 .. c*8+7
            int kg = c >> 2;            // k-group (32 d's)
            int q = c & 3;              // 8-d sub-chunk within k-group
            int i = i0 + s;
            int Ig = i >> 4;
            short8 wv;
            wv[0] = f2bf(gs[0]); wv[1] = f2bf(gs[1]); wv[2] = f2bf(gs[2]); wv[3] = f2bf(gs[3]);
            wv[4] = f2bf(h0);    wv[5] = f2bf(h1);    wv[6] = f2bf(h2);    wv[7] = f2bf(h3);
            *reinterpret_cast<short8*>(
                GbF + ((size_t)(Ig * 8 + kg) << 9) + ((i & 15) + 16 * q) * 8) = wv;
        }
    }
    if (t < 4) {
        hsum[i0 + t] = hsred[0][t] + hsred[1][t] + hsred[2][t] + hsred[3][t];
    } else if (t < 8) {
        int s = t - 4;
        hp2[i0 + s] = hqred[0][s] + hqred[1][s] + hqred[2][s] + hqred[3][s];
    }
}

// ---- som7: block 128n x 128i, 4 waves (2n x 2i), wave tile 64x64.
//      A (X) via LDS dbuf + global_load_lds; B (G) direct from L2 as
//      fragment-ordered global_load_dwordx4 into VGPRs. Counted vmcnt:
//      FIFO per phase = [B kk0(4), B kk1(4), Xnext(4)]; prev-X retired at
//      vmcnt(12), B kk0 at vmcnt(8), B kk1 at vmcnt(4). LDS 33KB. ----
__global__ void __launch_bounds__(256) som7_kernel(
    const short* __restrict__ Xg, const short* __restrict__ GbF,
    const float* __restrict__ x2, const float* __restrict__ hsum,
    const float* __restrict__ hp2, unsigned* __restrict__ out) {
    __shared__ __align__(16) short Xs[2][128 * 64];  // 16KB each
    __shared__ float red[2][128];

    const int t = threadIdx.x;
    const int lane = t & 63;
    const int wid = t >> 6;
    const int wr = wid >> 1;  // n half (64 rows)
    const int wc = wid & 1;   // i half (64 cols)
    const int lm = lane & 15;
    const int lq = lane >> 4;
    const int n0 = blockIdx.x * 128;
    const int ib0 = blockIdx.y * 128;
    const int Igbase = (ib0 >> 4) + wc * 4;

    f32x4 acc[4][4];
#pragma unroll
    for (int m = 0; m < 4; ++m)
#pragma unroll
        for (int n = 0; n < 4; ++n) acc[m][n] = (f32x4){0.f, 0.f, 0.f, 0.f};

    auto stage_X = [&](int xb, int kt) {
#pragma unroll
        for (int q = 0; q < 4; ++q) {
            int row = q * 32 + (t >> 3);
            gload_lds16((char*)(&Xs[xb][0]) + q * 4096 + t * 16,
                        Xg + (size_t)(n0 + row) * D + kt * 64 + (t & 7) * 8);
        }
    };

    // prologue: stage X for kt=0 (4 VMEM outstanding)
    stage_X(0, 0);

#pragma unroll
    for (int kt = 0; kt < 4; ++kt) {
        // B fragments for this K64 (both kk), straight from L2
        short8 b0[4], b1[4];
#pragma unroll
        for (int n = 0; n < 4; ++n) {
            const short* fb = GbF + ((size_t)((Igbase + n) * 8 + kt * 2) << 9) + lane * 8;
            b0[n] = *reinterpret_cast<const short8*>(fb);
            b1[n] = *reinterpret_cast<const short8*>(fb + 512);
        }
        __builtin_amdgcn_sched_barrier(0);  // pin FIFO: B before Xnext
        if (kt < 3) stage_X((kt + 1) & 1, kt + 1);
        if (kt < 3) { WAITVM(12); } else { WAITVM(8); }  // retire prev-phase X only
        __builtin_amdgcn_sched_barrier(0);
        __builtin_amdgcn_s_barrier();

        const short* xb = &Xs[kt & 1][0];
        // ---- kk = 0 ----
        {
            const int off = (lq * 8) ^ ((lm & 7) << 3);
            short8 a[4];
#pragma unroll
            for (int m = 0; m < 4; ++m)
                a[m] = *reinterpret_cast<const short8*>(
                    &xb[(wr * 64 + m * 16 + lm) * 64 + off]);
            if (kt < 3) { WAITVM(8); } else { WAITVM(4); }  // B kk0 ready
            __builtin_amdgcn_s_setprio(1);
#pragma unroll
            for (int m = 0; m < 4; ++m)
#pragma unroll
                for (int n = 0; n < 4; ++n)
                    acc[m][n] = __builtin_amdgcn_mfma_f32_16x16x32_bf16(a[m], b0[n], acc[m][n], 0, 0, 0);
            __builtin_amdgcn_s_setprio(0);
        }
        // ---- kk = 1 ----
        {
            const int off = (32 + lq * 8) ^ ((lm & 7) << 3);
            short8 a[4];
#pragma unroll
            for (int m = 0; m < 4; ++m)
                a[m] = *reinterpret_cast<const short8*>(
                    &xb[(wr * 64 + m * 16 + lm) * 64 + off]);
            if (kt < 3) { WAITVM(4); } else { WAITVM(0); }  // B kk1 ready (Xnext stays)
            __builtin_amdgcn_s_setprio(1);
#pragma unroll
            for (int m = 0; m < 4; ++m)
#pragma unroll
                for (int n = 0; n < 4; ++n)
                    acc[m][n] = __builtin_amdgcn_mfma_f32_16x16x32_bf16(a[m], b1[n], acc[m][n], 0, 0, 0);
            __builtin_amdgcn_s_setprio(0);
        }
        // single barrier per phase: dbuf makes a trailing barrier unnecessary
    }

    // ---- epilogue: e = hsum*x2 + hp2 - 2*acc; min over this block's 128 i ----
    float x2v[4][4];
#pragma unroll
    for (int m = 0; m < 4; ++m)
#pragma unroll
        for (int j = 0; j < 4; ++j)
            x2v[m][j] = x2[n0 + wr * 64 + m * 16 + lq * 4 + j];

    float rmin[4][4];
#pragma unroll
    for (int m = 0; m < 4; ++m)
#pragma unroll
        for (int j = 0; j < 4; ++j) rmin[m][j] = 3.4e38f;

#pragma unroll
    for (int ni = 0; ni < 4; ++ni) {
        int ig = ib0 + wc * 64 + ni * 16 + lm;
        float hs = hsum[ig];
        float hq = hp2[ig];
#pragma unroll
        for (int m = 0; m < 4; ++m)
#pragma unroll
            for (int j = 0; j < 4; ++j) {
                float e = fmaf(hs, x2v[m][j], hq) - 2.0f * acc[m][ni][j];
                rmin[m][j] = fminf(rmin[m][j], e);
            }
    }

#pragma unroll
    for (int m = 0; m < 4; ++m)
#pragma unroll
        for (int j = 0; j < 4; ++j) {
            float v = rmin[m][j];
            v = fminf(v, __shfl_xor(v, 1));
            v = fminf(v, __shfl_xor(v, 2));
            v = fminf(v, __shfl_xor(v, 4));
            v = fminf(v, __shfl_xor(v, 8));
            rmin[m][j] = v;
        }
    if (lm == 0) {
#pragma unroll
        for (int m = 0; m < 4; ++m)
#pragma unroll
            for (int j = 0; j < 4; ++j)
                red[wc][wr * 64 + m * 16 + lq * 4 + j] = rmin[m][j];
    }
    __syncthreads();
    if (t < 128) {
        float v = fminf(red[0][t], red[1][t]);
        atomicMin(out + n0 + t, __float_as_uint(0.5f * v));
    }
}

extern "C" void kernel_launch(void* const* d_in, const int* in_sizes, int n_in,
                              void* d_out, int out_size, void* d_ws, size_t ws_size,
                              hipStream_t stream) {
    const float* X = (const float*)d_in[0];  // [16384, 256]
    const float* P = (const float*)d_in[1];  // [1024, 256]
    unsigned* out = (unsigned*)d_out;        // [1, 16384] f32 as uint
    int N = in_sizes[0] / D;                 // 16384

    float* ws = (float*)d_ws;
    float* hsum = ws + 1024;             // 1024 f32
    float* hp2 = ws + 2048;              // 1024 f32
    float* x2 = ws + 4096;               // 16384 f32
    short* GbF = (short*)(ws + 32768);   // 1024*256 bf16 frag-ordered (512KB)
    short* Xg = (short*)(ws + 262144);   // 16384*256 bf16 (8.4MB) @ 1MB

    prep_kernel<<<GMAT_BLOCKS + XPREP_BLOCKS, 256, 0, stream>>>(
        X, P, Xg, GbF, x2, hsum, hp2, out);
    som7_kernel<<<dim3(N / 128, NPROTO / 128), 256, 0, stream>>>(
        Xg, GbF, x2, hsum, hp2, out);
}